// Round 6
// baseline (341.590 us; speedup 1.0000x reference)
//
#include <hip/hip_runtime.h>
#include <hip/hip_bf16.h>
#include <stdint.h>

typedef short bf16x8 __attribute__((ext_vector_type(8)));
typedef float f32x4 __attribute__((ext_vector_type(4)));
typedef float f32x16 __attribute__((ext_vector_type(16)));
typedef unsigned int uint4v __attribute__((ext_vector_type(4)));

#define NB 4
#define NL 2048
#define ND 1024
#define NH 16
#define NDK 64
#define NM (NB*NL)
// 1/sqrt(DK) * log2(e): folded into Q at the QKV-GEMM epilogue -> softmax in exp2 domain
#define QSCALE 0.18033688011112042f

__device__ __forceinline__ ushort f2bf(float f) {
  __bf16 h = (__bf16)f;
  return __builtin_bit_cast(unsigned short, h);
}

__device__ __forceinline__ unsigned int cvtpk(float lo, float hi) {
  unsigned int d;
  asm("v_cvt_pk_bf16_f32 %0, %1, %2" : "=v"(d) : "v"(lo), "v"(hi));
  return d;
}

// async global->LDS, 16B per lane. lds base must be wave-uniform; HW adds lane*16.
__device__ __forceinline__ void gload16(const void* g, void* l) {
  __builtin_amdgcn_global_load_lds(
      (__attribute__((address_space(1))) void*)(uintptr_t)g,
      (__attribute__((address_space(3))) void*)(uint32_t)(uintptr_t)l,
      16, 0, 0);
}

__device__ __forceinline__ f32x16 mfma32(bf16x8 a, bf16x8 b, f32x16 c) {
  return __builtin_amdgcn_mfma_f32_32x32x16_bf16(a, b, c, 0, 0, 0);
}

// ---------------- fp32 -> bf16 conversion of x, Wq, Wk, Wv, Wo ----------------
__global__ void convert_all(const float* __restrict__ x, const float* __restrict__ wq,
                            const float* __restrict__ wk, const float* __restrict__ wv,
                            const float* __restrict__ wo, ushort* __restrict__ o) {
  long i = (long)blockIdx.x * 256 + threadIdx.x;   // float4 index
  const long NX = 2097152;   // x float4s
  const long NW = 262144;    // per-W float4s
  const float4* s;
  long off;
  if (i < NX) { s = (const float4*)x; off = i; }
  else {
    long j = i - NX;
    int wsel = (int)(j >> 18);
    off = j & (NW - 1);
    s = (const float4*)(wsel == 0 ? wq : wsel == 1 ? wk : wsel == 2 ? wv : wo);
  }
  float4 v = s[off];
  ushort4 r;
  r.x = f2bf(v.x); r.y = f2bf(v.y); r.z = f2bf(v.z); r.w = f2bf(v.w);
  ((ushort4*)o)[i] = r;
}

// ---------------- GEMM: C[m,n] = sum_k A[m,k] * B[n,k]  (B^T layout) ----------------
// MODE 0: A=x_bf16; B in {Wq,Wk,Wv}; Q out pre-scaled by QSCALE [B,H,L,DK]; K [B,H,L,DK]; V [B,H,DK,L]
// MODE 1: A=attnout; B=Wo; out fp32 [8192,1024]
template<int MODE>
__global__ __launch_bounds__(256, 2)
void gemm_bt(const ushort* __restrict__ A,
             const ushort* __restrict__ Bq, const ushort* __restrict__ Bk, const ushort* __restrict__ Bv,
             ushort* __restrict__ Oq, ushort* __restrict__ Ok, ushort* __restrict__ Ov,
             float* __restrict__ OF) {
  __shared__ __align__(16) ushort lA[128 * 32];
  __shared__ __align__(16) ushort lB[128 * 32];
  const int t = threadIdx.x;
  const int w = t >> 6, l = t & 63;
  const int lr = l & 15, lh = l >> 4;
  // bijective XCD swizzle on the m-tile index (gridDim.x == 64, 64%8==0)
  const int bxr = blockIdx.x;
  const int bx = (bxr & 7) * 8 + (bxr >> 3);
  const int m0 = bx * 128;
  const int ng = blockIdx.y * 128;
  const ushort* Bp;
  ushort* Op = nullptr;
  int mi = 0, n0;
  if (MODE == 0) {
    mi = ng >> 10;
    Bp = (mi == 0) ? Bq : (mi == 1) ? Bk : Bv;
    Op = (mi == 0) ? Oq : (mi == 1) ? Ok : Ov;
    n0 = ng & 1023;
  } else {
    Bp = Bq;
    n0 = ng;
  }
  const int wrow = (w >> 1) * 64, wcol = (w & 1) * 64;
  const int r = t >> 2, c = t & 3;
  const ushort* gA0 = A + (size_t)(m0 + r) * ND + c * 8;
  const ushort* gA1 = A + (size_t)(m0 + 64 + r) * ND + c * 8;
  const ushort* gB0 = Bp + (size_t)(n0 + r) * ND + c * 8;
  const ushort* gB1 = Bp + (size_t)(n0 + 64 + r) * ND + c * 8;
  ushort* lA0 = lA + (w * 64) * 8;
  ushort* lA1 = lA + (256 + w * 64) * 8;
  ushort* lB0 = lB + (w * 64) * 8;
  ushort* lB1 = lB + (256 + w * 64) * 8;

  f32x4 acc[4][4] = {};
  for (int kt = 0; kt < ND; kt += 32) {
    __syncthreads();
    gload16(gA0 + kt, lA0);
    gload16(gA1 + kt, lA1);
    gload16(gB0 + kt, lB0);
    gload16(gB1 + kt, lB1);
    __syncthreads();
    bf16x8 af[4], bfr[4];
#pragma unroll
    for (int mt = 0; mt < 4; mt++)
      af[mt] = *(const bf16x8*)&lA[(wrow + mt * 16 + lr) * 32 + lh * 8];
#pragma unroll
    for (int nt = 0; nt < 4; nt++)
      bfr[nt] = *(const bf16x8*)&lB[(wcol + nt * 16 + lr) * 32 + lh * 8];
#pragma unroll
    for (int mt = 0; mt < 4; mt++)
#pragma unroll
      for (int nt = 0; nt < 4; nt++)
        acc[mt][nt] = __builtin_amdgcn_mfma_f32_16x16x32_bf16(af[mt], bfr[nt], acc[mt][nt], 0, 0, 0);
  }
  // epilogue: C/D layout col = lane&15, row = (lane>>4)*4 + reg
#pragma unroll
  for (int mt = 0; mt < 4; mt++) {
#pragma unroll
    for (int nt = 0; nt < 4; nt++) {
#pragma unroll
      for (int j = 0; j < 4; j++) {
        int m = m0 + wrow + mt * 16 + lh * 4 + j;
        int n = wcol + nt * 16 + lr;
        if (MODE == 0) {
          int nl = n0 + n;
          int b = m >> 11, ll = m & 2047;
          int h = nl >> 6, dk = nl & 63;
          float v = acc[mt][nt][j];
          if (mi == 0) v *= QSCALE;   // fold softmax scale+log2e into Q
          if (mi == 2)  // V stored transposed: [B,H,DK,L]
            Op[(((size_t)(b * NH + h)) * NDK + dk) * NL + ll] = f2bf(v);
          else
            Op[(((size_t)(b * NH + h)) * NL + ll) * NDK + dk] = f2bf(v);
        } else {
          OF[(size_t)m * ND + ng + n] = acc[mt][nt][j];
        }
      }
    }
  }
}

// ---------------- causal flash attention, 4-wave, deep K-pipeline ----------------
// Flat grid 1024 blocks, 256 threads. Work (bh, qt) remapped so each CU's 4 resident
// blocks get qt-set {g, 7-g, 8+g, 15-g} (sum const -> balanced makespan).
// K: LDS 4-deep ring (8 KB/tile), counted vmcnt(4) + raw s_barrier -> stage latency
// budget ~3 phases (T3+T4). V: direct global->VGPR, issued early, consumed after
// softmax (latency hidden under QK+softmax VALU). Softmax exp2-domain, Q pre-scaled.
__global__ __launch_bounds__(256, 4)
void attn_fwd(const ushort* __restrict__ Q, const ushort* __restrict__ Kg,
              const ushort* __restrict__ VT, ushort* __restrict__ O) {
  __shared__ __align__(16) ushort lK[4][64 * 64];   // 4-deep ring, swizzled chunks
  const int t = threadIdx.x;
  const int w = t >> 6, l = t & 63;
  const int l31 = l & 31, hi = l >> 5;
  // balanced (bh, qt) assignment
  const int id = blockIdx.x;
  const int bh = id & 63;
  const int g = (id >> 6) & 3;
  const int k4 = id >> 8;
  const int qt = (k4 == 0) ? g : (k4 == 1) ? 7 - g : (k4 == 2) ? 8 + g : 15 - g;
  const size_t base = (size_t)bh * (NL * NDK);
  const int q0w = qt * 128 + w * 32;
  const int ktmax = q0w >> 6;          // wave's diagonal 64-kv tile
  const int NT = qt * 2 + 2;           // tiles the block stages

  // Q fragments (pre-scaled): qf[sl] = Q[q0w + l31][sl*16 + hi*8 .. +8]
  bf16x8 qf[4];
  {
    const ushort* qp = Q + base + (size_t)(q0w + l31) * NDK + hi * 8;
#pragma unroll
    for (int sl = 0; sl < 4; sl++) qf[sl] = *(const bf16x8*)(qp + sl * 16);
  }

  // K staging: 512 16B-slots per tile; thread t covers slots {t, t+256}.
  // slot s -> row = s>>3, chunk = s&7; source chunk pre-swizzled ^(row&7); LDS linear.
  const int kr0 = t >> 3, kc0 = (t & 7) ^ (kr0 & 7);
  const int sB = t + 256;
  const int kr1 = sB >> 3, kc1 = (sB & 7) ^ (kr1 & 7);
  const ushort* gK0 = Kg + base + (size_t)kr0 * NDK + kc0 * 8;
  const ushort* gK1 = Kg + base + (size_t)kr1 * NDK + kc1 * 8;
  // V direct pointers (V^T rows = dk)
  const ushort* vp0 = VT + base + (size_t)l31 * NL + hi * 8;
  const ushort* vp1 = VT + base + (size_t)(32 + l31) * NL + hi * 8;

  float m_run = -1e30f, l_run = 0.f;
  f32x16 accO0 = {}, accO1 = {};
  const int swz = l31 & 7;

#define STAGEK(bufi, kti) do {                                      \
    const size_t kvo = (size_t)(kti) * 64 * NDK;                    \
    gload16(gK0 + kvo, &lK[bufi][w * 512]);                         \
    gload16(gK1 + kvo, &lK[bufi][2048 + w * 512]);                  \
  } while (0)

  // prologue: 3-deep prefetch
  STAGEK(0, 0);
  if (NT > 1) STAGEK(1, 1); else STAGEK(1, 0);
  if (NT > 2) STAGEK(2, 2); else STAGEK(2, 0);

  for (int kt = 0; kt < NT; kt++) {
    // own stage(kt) complete; stages kt+1, kt+2 (2 loads each) remain in flight
    asm volatile("s_waitcnt vmcnt(4)" ::: "memory");
    __builtin_amdgcn_s_barrier();          // all waves' stage(kt) done; compute(kt-1) closed
    __builtin_amdgcn_sched_barrier(0);     // keep the next stage from hoisting above barrier
    {
      const int st = (kt + 3 < NT) ? kt + 3 : NT - 1;   // dummy re-stage keeps vmcnt uniform
      STAGEK((kt + 3) & 3, st);
    }
    if (kt <= ktmax) {
      const ushort* bK = lK[kt & 3];
      // mode: 0 full; 1 diagonal even-w (skip upper kv half); 2 diagonal odd-w
      const int mode = (kt < ktmax) ? 0 : ((w & 1) ? 2 : 1);
      // ---- K fragments from LDS ----
      bf16x8 kf0[4], kf1[4];
#pragma unroll
      for (int sl = 0; sl < 4; sl++) {
        int c = 2 * sl + hi;
        kf0[sl] = *(const bf16x8*)&bK[l31 * 64 + ((c ^ swz) * 8)];
      }
      if (mode != 1) {
#pragma unroll
        for (int sl = 0; sl < 4; sl++) {
          int c = 2 * sl + hi;
          kf1[sl] = *(const bf16x8*)&bK[(32 + l31) * 64 + ((c ^ swz) * 8)];
        }
      }
      // ---- issue V loads now; consumed after softmax (latency hidden) ----
      const int kv0 = kt * 64;
      bf16x8 vf0[4], vf1[4];
#pragma unroll
      for (int ks = 0; ks < 2; ks++) {
        vf0[ks] = *(const bf16x8*)(vp0 + kv0 + ks * 16);
        vf1[ks] = *(const bf16x8*)(vp1 + kv0 + ks * 16);
      }
      if (mode != 1) {
#pragma unroll
        for (int ks = 2; ks < 4; ks++) {
          vf0[ks] = *(const bf16x8*)(vp0 + kv0 + ks * 16);
          vf1[ks] = *(const bf16x8*)(vp1 + kv0 + ks * 16);
        }
      }
      // ---- QK^T: S^T[kv][q], exp2 domain ----
      f32x16 s0 = {}, s1 = {};
      __builtin_amdgcn_s_setprio(1);
#pragma unroll
      for (int sl = 0; sl < 4; sl++) s0 = mfma32(kf0[sl], qf[sl], s0);
      if (mode != 1) {
#pragma unroll
        for (int sl = 0; sl < 4; sl++) s1 = mfma32(kf1[sl], qf[sl], s1);
      }
      __builtin_amdgcn_s_setprio(0);
      // ---- causal mask (diagonal tiles only) ----
      if (mode == 1) {
#pragma unroll
        for (int r = 0; r < 16; r++) {
          int kvo = (r & 3) + 8 * (r >> 2) + 4 * hi;
          if (kvo > l31) s0[r] = -1e30f;
        }
      } else if (mode == 2) {
#pragma unroll
        for (int r = 0; r < 16; r++) {
          int kvo = (r & 3) + 8 * (r >> 2) + 4 * hi;
          if (kvo > l31) s1[r] = -1e30f;
        }
      }
      // ---- online softmax, exp2 domain (q lane-local; halves combine via xor-32) ----
      float mx = s0[0];
#pragma unroll
      for (int r = 1; r < 16; r++) mx = fmaxf(mx, s0[r]);
      if (mode != 1) {
#pragma unroll
        for (int r = 0; r < 16; r++) mx = fmaxf(mx, s1[r]);
      }
      mx = fmaxf(mx, __shfl_xor(mx, 32));
      float fscale = 1.0f;
      if (!__all(mx <= m_run + 11.0f)) {   // defer-max (T13), 2^11 headroom
        float mn = fmaxf(m_run, mx);
        fscale = exp2f(m_run - mn);
        m_run = mn;
#pragma unroll
        for (int r = 0; r < 16; r++) { accO0[r] *= fscale; accO1[r] *= fscale; }
      }
      float sum = 0.f;
#pragma unroll
      for (int r = 0; r < 16; r++) { s0[r] = exp2f(s0[r] - m_run); sum += s0[r]; }
      if (mode != 1) {
#pragma unroll
        for (int r = 0; r < 16; r++) { s1[r] = exp2f(s1[r] - m_run); sum += s1[r]; }
      }
      sum += __shfl_xor(sum, 32);
      l_run = l_run * fscale + sum;
      // ---- pack P^T fragments: pa[ks] = P[q=l&31][kv = ks*16 + hi*8 + j] ----
      bf16x8 pa[4];
#pragma unroll
      for (int ks = 0; ks < 2; ks++) {
        const int k2 = ks * 8;
        unsigned int a0 = cvtpk(s0[k2 + 0], s0[k2 + 1]), a1 = cvtpk(s0[k2 + 2], s0[k2 + 3]);
        unsigned int b0 = cvtpk(s0[k2 + 4], s0[k2 + 5]), b1 = cvtpk(s0[k2 + 6], s0[k2 + 7]);
        unsigned int a0s = __shfl_xor(a0, 32), a1s = __shfl_xor(a1, 32);
        unsigned int b0s = __shfl_xor(b0, 32), b1s = __shfl_xor(b1, 32);
        uint4v pd;
        pd[0] = hi ? b0s : a0;
        pd[1] = hi ? b1s : a1;
        pd[2] = hi ? b0 : a0s;
        pd[3] = hi ? b1 : a1s;
        pa[ks] = __builtin_bit_cast(bf16x8, pd);
      }
      if (mode != 1) {
#pragma unroll
        for (int ks = 2; ks < 4; ks++) {
          const int k2 = (ks - 2) * 8;
          unsigned int a0 = cvtpk(s1[k2 + 0], s1[k2 + 1]), a1 = cvtpk(s1[k2 + 2], s1[k2 + 3]);
          unsigned int b0 = cvtpk(s1[k2 + 4], s1[k2 + 5]), b1 = cvtpk(s1[k2 + 6], s1[k2 + 7]);
          unsigned int a0s = __shfl_xor(a0, 32), a1s = __shfl_xor(a1, 32);
          unsigned int b0s = __shfl_xor(b0, 32), b1s = __shfl_xor(b1, 32);
          uint4v pd;
          pd[0] = hi ? b0s : a0;
          pd[1] = hi ? b1s : a1;
          pd[2] = hi ? b0 : a0s;
          pd[3] = hi ? b1 : a1s;
          pa[ks] = __builtin_bit_cast(bf16x8, pd);
        }
      }
      // ---- PV: O^T += V^T-frag x P^T-frag ----
      __builtin_amdgcn_s_setprio(1);
      accO0 = mfma32(vf0[0], pa[0], accO0);
      accO1 = mfma32(vf1[0], pa[0], accO1);
      accO0 = mfma32(vf0[1], pa[1], accO0);
      accO1 = mfma32(vf1[1], pa[1], accO1);
      if (mode != 1) {
        accO0 = mfma32(vf0[2], pa[2], accO0);
        accO1 = mfma32(vf1[2], pa[2], accO1);
        accO0 = mfma32(vf0[3], pa[3], accO0);
        accO1 = mfma32(vf1[3], pa[3], accO1);
      }
      __builtin_amdgcn_s_setprio(0);
    }
  }
#undef STAGEK
  // ---- epilogue: lane l holds O[q = q0w + l31][dk = (r&3)+8*(r>>2)+4*hi (+32)] ----
  const int b = bh >> 4, h = bh & 15;
  const float inv = 1.0f / l_run;
  const int q = q0w + l31;
  ushort* orow = O + ((size_t)b * NL + q) * ND + h * NDK;
#pragma unroll
  for (int gi = 0; gi < 4; gi++) {
    ushort4 o0, o1;
    o0.x = f2bf(accO0[4 * gi + 0] * inv); o0.y = f2bf(accO0[4 * gi + 1] * inv);
    o0.z = f2bf(accO0[4 * gi + 2] * inv); o0.w = f2bf(accO0[4 * gi + 3] * inv);
    o1.x = f2bf(accO1[4 * gi + 0] * inv); o1.y = f2bf(accO1[4 * gi + 1] * inv);
    o1.z = f2bf(accO1[4 * gi + 2] * inv); o1.w = f2bf(accO1[4 * gi + 3] * inv);
    *(ushort4*)&orow[8 * gi + 4 * hi] = o0;
    *(ushort4*)&orow[32 + 8 * gi + 4 * hi] = o1;
  }
}

extern "C" void kernel_launch(void* const* d_in, const int* in_sizes, int n_in,
                              void* d_out, int out_size, void* d_ws, size_t ws_size,
                              hipStream_t stream) {
  const float* x = (const float*)d_in[0];
  const float* wq = (const float*)d_in[1];
  const float* wk = (const float*)d_in[2];
  const float* wv = (const float*)d_in[3];
  const float* wo = (const float*)d_in[4];
  char* ws = (char*)d_ws;
  ushort* xb  = (ushort*)(ws);               // 16,777,216 B
  ushort* wqb = (ushort*)(ws + 16777216);
  ushort* wkb = (ushort*)(ws + 18874368);
  ushort* wvb = (ushort*)(ws + 20971520);
  ushort* wob = (ushort*)(ws + 23068672);
  ushort* Qb  = (ushort*)(ws + 25165824);    // [B,H,L,DK] bf16, pre-scaled
  ushort* Kb  = (ushort*)(ws + 41943040);    // [B,H,L,DK]
  ushort* Vb  = (ushort*)(ws + 58720256);    // [B,H,DK,L] (transposed)
  ushort* Ob  = (ushort*)(ws + 75497472);    // [B,L,D] bf16

  convert_all<<<12288, 256, 0, stream>>>(x, wq, wk, wv, wo, xb);
  gemm_bt<0><<<dim3(64, 24), 256, 0, stream>>>(xb, wqb, wkb, wvb, Qb, Kb, Vb, nullptr);
  attn_fwd<<<dim3(1024), 256, 0, stream>>>(Qb, Kb, Vb, Ob);
  gemm_bt<1><<<dim3(64, 8), 256, 0, stream>>>(Ob, wob, nullptr, nullptr,
                                              nullptr, nullptr, nullptr, (float*)d_out);
}

// Round 7
// 185.603 us; speedup vs baseline: 1.8404x; 1.8404x over previous
//
#include <hip/hip_runtime.h>
#include <hip/hip_bf16.h>
#include <stdint.h>

typedef short bf16x8 __attribute__((ext_vector_type(8)));
typedef float f32x4 __attribute__((ext_vector_type(4)));
typedef float f32x16 __attribute__((ext_vector_type(16)));
typedef unsigned int uint4v __attribute__((ext_vector_type(4)));

#define NB 4
#define NL 2048
#define ND 1024
#define NH 16
#define NDK 64
#define NM (NB*NL)
// 1/sqrt(DK) * log2(e): folded into Q at the QKV-GEMM epilogue -> softmax in exp2 domain
#define QSCALE 0.18033688011112042f

__device__ __forceinline__ ushort f2bf(float f) {
  __bf16 h = (__bf16)f;
  return __builtin_bit_cast(unsigned short, h);
}

__device__ __forceinline__ unsigned int cvtpk(float lo, float hi) {
  unsigned int d;
  asm("v_cvt_pk_bf16_f32 %0, %1, %2" : "=v"(d) : "v"(lo), "v"(hi));
  return d;
}

// async global->LDS, 16B per lane. lds base must be wave-uniform; HW adds lane*16.
__device__ __forceinline__ void gload16(const void* g, void* l) {
  __builtin_amdgcn_global_load_lds(
      (__attribute__((address_space(1))) void*)(uintptr_t)g,
      (__attribute__((address_space(3))) void*)(uint32_t)(uintptr_t)l,
      16, 0, 0);
}

__device__ __forceinline__ f32x16 mfma32(bf16x8 a, bf16x8 b, f32x16 c) {
  return __builtin_amdgcn_mfma_f32_32x32x16_bf16(a, b, c, 0, 0, 0);
}

// ---------------- fp32 -> bf16 conversion of x, Wq, Wk, Wv, Wo ----------------
__global__ void convert_all(const float* __restrict__ x, const float* __restrict__ wq,
                            const float* __restrict__ wk, const float* __restrict__ wv,
                            const float* __restrict__ wo, ushort* __restrict__ o) {
  long i = (long)blockIdx.x * 256 + threadIdx.x;   // float4 index
  const long NX = 2097152;   // x float4s
  const long NW = 262144;    // per-W float4s
  const float4* s;
  long off;
  if (i < NX) { s = (const float4*)x; off = i; }
  else {
    long j = i - NX;
    int wsel = (int)(j >> 18);
    off = j & (NW - 1);
    s = (const float4*)(wsel == 0 ? wq : wsel == 1 ? wk : wsel == 2 ? wv : wo);
  }
  float4 v = s[off];
  ushort4 r;
  r.x = f2bf(v.x); r.y = f2bf(v.y); r.z = f2bf(v.z); r.w = f2bf(v.w);
  ((ushort4*)o)[i] = r;
}

// ---------------- GEMM: C[m,n] = sum_k A[m,k] * B[n,k]  (B^T layout) ----------------
// Double-buffered LDS, ONE __syncthreads per K-step: stage(kt+1) issued right after
// barrier(kt), so staging latency hides under compute(kt) instead of being drained
// immediately (old 2-barrier structure exposed the full stage latency every step).
// MODE 0: A=x_bf16; B in {Wq,Wk,Wv}; Q out pre-scaled by QSCALE [B,H,L,DK]; K [B,H,L,DK]; V [B,H,DK,L]
// MODE 1: A=attnout; B=Wo; out fp32 [8192,1024]
template<int MODE>
__global__ __launch_bounds__(256, 2)
void gemm_bt(const ushort* __restrict__ A,
             const ushort* __restrict__ Bq, const ushort* __restrict__ Bk, const ushort* __restrict__ Bv,
             ushort* __restrict__ Oq, ushort* __restrict__ Ok, ushort* __restrict__ Ov,
             float* __restrict__ OF) {
  __shared__ __align__(16) ushort lA[2][128 * 32];
  __shared__ __align__(16) ushort lB[2][128 * 32];
  const int t = threadIdx.x;
  const int w = t >> 6, l = t & 63;
  const int lr = l & 15, lh = l >> 4;
  // bijective XCD swizzle on the m-tile index (gridDim.x == 64, 64%8==0)
  const int bxr = blockIdx.x;
  const int bx = (bxr & 7) * 8 + (bxr >> 3);
  const int m0 = bx * 128;
  const int ng = blockIdx.y * 128;
  const ushort* Bp;
  ushort* Op = nullptr;
  int mi = 0, n0;
  if (MODE == 0) {
    mi = ng >> 10;
    Bp = (mi == 0) ? Bq : (mi == 1) ? Bk : Bv;
    Op = (mi == 0) ? Oq : (mi == 1) ? Ok : Ov;
    n0 = ng & 1023;
  } else {
    Bp = Bq;
    n0 = ng;
  }
  const int wrow = (w >> 1) * 64, wcol = (w & 1) * 64;
  const int r = t >> 2, c = t & 3;
  const ushort* gA0 = A + (size_t)(m0 + r) * ND + c * 8;
  const ushort* gA1 = A + (size_t)(m0 + 64 + r) * ND + c * 8;
  const ushort* gB0 = Bp + (size_t)(n0 + r) * ND + c * 8;
  const ushort* gB1 = Bp + (size_t)(n0 + 64 + r) * ND + c * 8;

#define GSTAGE(bi, kofs) do {                              \
    gload16(gA0 + (kofs), &lA[bi][w * 512]);               \
    gload16(gA1 + (kofs), &lA[bi][2048 + w * 512]);        \
    gload16(gB0 + (kofs), &lB[bi][w * 512]);               \
    gload16(gB1 + (kofs), &lB[bi][2048 + w * 512]);        \
  } while (0)

  GSTAGE(0, 0);
  f32x4 acc[4][4] = {};
  for (int kt = 0; kt < ND; kt += 32) {
    const int buf = (kt >> 5) & 1;
    __syncthreads();                       // stage(kt) complete; compute(kt-1) closed
    if (kt + 32 < ND) GSTAGE(buf ^ 1, kt + 32);
    bf16x8 af[4], bfr[4];
#pragma unroll
    for (int mt = 0; mt < 4; mt++)
      af[mt] = *(const bf16x8*)&lA[buf][(wrow + mt * 16 + lr) * 32 + lh * 8];
#pragma unroll
    for (int nt = 0; nt < 4; nt++)
      bfr[nt] = *(const bf16x8*)&lB[buf][(wcol + nt * 16 + lr) * 32 + lh * 8];
#pragma unroll
    for (int mt = 0; mt < 4; mt++)
#pragma unroll
      for (int nt = 0; nt < 4; nt++)
        acc[mt][nt] = __builtin_amdgcn_mfma_f32_16x16x32_bf16(af[mt], bfr[nt], acc[mt][nt], 0, 0, 0);
  }
#undef GSTAGE
  // epilogue: C/D layout col = lane&15, row = (lane>>4)*4 + reg
#pragma unroll
  for (int mt = 0; mt < 4; mt++) {
#pragma unroll
    for (int nt = 0; nt < 4; nt++) {
#pragma unroll
      for (int j = 0; j < 4; j++) {
        int m = m0 + wrow + mt * 16 + lh * 4 + j;
        int n = wcol + nt * 16 + lr;
        if (MODE == 0) {
          int nl = n0 + n;
          int b = m >> 11, ll = m & 2047;
          int h = nl >> 6, dk = nl & 63;
          float v = acc[mt][nt][j];
          if (mi == 0) v *= QSCALE;   // fold softmax scale+log2e into Q
          if (mi == 2)  // V stored transposed: [B,H,DK,L]
            Op[(((size_t)(b * NH + h)) * NDK + dk) * NL + ll] = f2bf(v);
          else
            Op[(((size_t)(b * NH + h)) * NL + ll) * NDK + dk] = f2bf(v);
        } else {
          OF[(size_t)m * ND + ng + n] = acc[mt][nt][j];
        }
      }
    }
  }
}

// ---------------- causal flash attention, 4-wave 32x32 swapped-operand ----------------
// Flat grid 1024 blocks, 256 threads (round-4 structure; no spills). Balanced work map:
// bh = id&63 (keeps bh%8 -> XCD for K/V L2 locality); qt from exact-cover table
// {g, 7-g, 8+g, 15-g} so each CU's 4 resident blocks sum to a constant 68 phases.
// S^T = mfma(K,Q): q = lane&31 lane-local; softmax exp2-domain (Q pre-scaled).
__global__ __launch_bounds__(256, 4)
void attn_fwd(const ushort* __restrict__ Q, const ushort* __restrict__ Kg,
              const ushort* __restrict__ VT, ushort* __restrict__ O) {
  __shared__ __align__(16) ushort lK[2][64 * 64];   // [kv][d], swizzled chunks
  __shared__ __align__(16) ushort lV[2][64 * 64];   // [dk][kv], swizzled chunks
  const int t = threadIdx.x;
  const int w = t >> 6, l = t & 63;
  const int l31 = l & 31, hi = l >> 5;
  const int id = blockIdx.x;
  const int bh = id & 63;
  const int g = (id >> 6) & 3;
  const int k4 = id >> 8;
  const int qt = (k4 == 0) ? g : (k4 == 1) ? 7 - g : (k4 == 2) ? 8 + g : 15 - g;
  const size_t base = (size_t)bh * (NL * NDK);
  const int q0w = qt * 128 + w * 32;
  const int ktmax = q0w >> 6;          // wave's diagonal 64-kv tile
  const int NT = qt * 2 + 2;           // tiles the block must stage

  // Q fragments (pre-scaled by QSCALE): qf[sl] = Q[q0w + l31][sl*16 + hi*8 .. +8]
  bf16x8 qf[4];
  {
    const ushort* qp = Q + base + (size_t)(q0w + l31) * NDK + hi * 8;
#pragma unroll
    for (int sl = 0; sl < 4; sl++) qf[sl] = *(const bf16x8*)(qp + sl * 16);
  }

  // staging: 512 16B-slots per operand per tile; thread t covers slots {t, t+256}.
  // slot s -> row = s>>3, chunk = s&7; source chunk pre-swizzled: ^(row&7); LDS linear.
  const int kr0 = t >> 3, kc0 = (t & 7) ^ (kr0 & 7);
  const int s1 = t + 256;
  const int kr1 = s1 >> 3, kc1 = (s1 & 7) ^ (kr1 & 7);
  const ushort* gK0 = Kg + base + (size_t)kr0 * NDK + kc0 * 8;
  const ushort* gK1 = Kg + base + (size_t)kr1 * NDK + kc1 * 8;
  const ushort* gV0 = VT + base + (size_t)kr0 * NL + kc0 * 8;
  const ushort* gV1 = VT + base + (size_t)kr1 * NL + kc1 * 8;

  float m_run = -1e30f, l_run = 0.f;
  f32x16 accO0 = {}, accO1 = {};
  const int swz = l31 & 7;

#define STAGE(bufi, kt1) do {                                       \
    const size_t kvn = (size_t)(kt1) * 64;                          \
    gload16(gK0 + kvn * NDK, &lK[bufi][w * 512]);                   \
    gload16(gK1 + kvn * NDK, &lK[bufi][2048 + w * 512]);            \
    gload16(gV0 + kvn, &lV[bufi][w * 512]);                         \
    gload16(gV1 + kvn, &lV[bufi][2048 + w * 512]);                  \
  } while (0)

  STAGE(0, 0);

  for (int kt = 0; kt < NT; kt++) {
    const int buf = kt & 1;
    __syncthreads();   // stage(kt) complete (vmcnt drained) + compute(kt-1) closed
    if (kt + 1 < NT) STAGE(buf ^ 1, kt + 1);
    if (kt <= ktmax) {
      const int kv0 = kt * 64;
      const ushort* bK = lK[buf];
      const ushort* bV = lV[buf];
      // ---- QK^T: S^T[kv][q]; kv halves s0 (0..31), s1 (32..63); log2 domain ----
      f32x16 s0 = {}, s1v = {};
      __builtin_amdgcn_s_setprio(1);
#pragma unroll
      for (int sl = 0; sl < 4; sl++) {
        int c = 2 * sl + hi;
        bf16x8 kf0 = *(const bf16x8*)&bK[l31 * 64 + ((c ^ swz) * 8)];
        bf16x8 kf1 = *(const bf16x8*)&bK[(32 + l31) * 64 + ((c ^ swz) * 8)];
        s0 = mfma32(kf0, qf[sl], s0);
        s1v = mfma32(kf1, qf[sl], s1v);
      }
      __builtin_amdgcn_s_setprio(0);
      // causal mask on the wave's diagonal tile
      if (kt == ktmax) {
        const int qrel = q0w + l31 - kv0;
#pragma unroll
        for (int r = 0; r < 16; r++) {
          int kvo = (r & 3) + 8 * (r >> 2) + 4 * hi;
          if (kvo > qrel) s0[r] = -1e30f;
          if (kvo + 32 > qrel) s1v[r] = -1e30f;
        }
      }
      // ---- online softmax, exp2 domain (q lane-local; halves combine via xor-32) ----
      float mx = s0[0];
#pragma unroll
      for (int r = 1; r < 16; r++) mx = fmaxf(mx, s0[r]);
#pragma unroll
      for (int r = 0; r < 16; r++) mx = fmaxf(mx, s1v[r]);
      mx = fmaxf(mx, __shfl_xor(mx, 32));
      float fscale = 1.0f;
      if (!__all(mx <= m_run + 11.0f)) {   // defer-max (T13), 2^11 headroom
        float mn = fmaxf(m_run, mx);
        fscale = exp2f(m_run - mn);
        m_run = mn;
#pragma unroll
        for (int r = 0; r < 16; r++) { accO0[r] *= fscale; accO1[r] *= fscale; }
      }
      float sum = 0.f;
#pragma unroll
      for (int r = 0; r < 16; r++) { s0[r] = exp2f(s0[r] - m_run); sum += s0[r]; }
#pragma unroll
      for (int r = 0; r < 16; r++) { s1v[r] = exp2f(s1v[r] - m_run); sum += s1v[r]; }
      sum += __shfl_xor(sum, 32);
      l_run = l_run * fscale + sum;
      // ---- pack P^T fragments: pa[ks] = P[q=l&31][kv = ks*16 + hi*8 + j] ----
      bf16x8 pa[4];
#pragma unroll
      for (int ks = 0; ks < 4; ks++) {
        const int k2 = (ks & 1) * 8;
        unsigned int a0, a1, b0, b1;
        if (ks >> 1) {
          a0 = cvtpk(s1v[k2 + 0], s1v[k2 + 1]); a1 = cvtpk(s1v[k2 + 2], s1v[k2 + 3]);
          b0 = cvtpk(s1v[k2 + 4], s1v[k2 + 5]); b1 = cvtpk(s1v[k2 + 6], s1v[k2 + 7]);
        } else {
          a0 = cvtpk(s0[k2 + 0], s0[k2 + 1]); a1 = cvtpk(s0[k2 + 2], s0[k2 + 3]);
          b0 = cvtpk(s0[k2 + 4], s0[k2 + 5]); b1 = cvtpk(s0[k2 + 6], s0[k2 + 7]);
        }
        unsigned int a0s = __shfl_xor(a0, 32), a1s = __shfl_xor(a1, 32);
        unsigned int b0s = __shfl_xor(b0, 32), b1s = __shfl_xor(b1, 32);
        uint4v pd;
        pd[0] = hi ? b0s : a0;
        pd[1] = hi ? b1s : a1;
        pd[2] = hi ? b0 : a0s;
        pd[3] = hi ? b1 : a1s;
        pa[ks] = __builtin_bit_cast(bf16x8, pd);
      }
      // ---- PV: O^T += V^T-frag x P^T-frag ----
      __builtin_amdgcn_s_setprio(1);
#pragma unroll
      for (int ks = 0; ks < 4; ks++) {
        int c = 2 * ks + hi;
        bf16x8 vf0 = *(const bf16x8*)&bV[l31 * 64 + ((c ^ swz) * 8)];
        bf16x8 vf1 = *(const bf16x8*)&bV[(32 + l31) * 64 + ((c ^ swz) * 8)];
        accO0 = mfma32(vf0, pa[ks], accO0);
        accO1 = mfma32(vf1, pa[ks], accO1);
      }
      __builtin_amdgcn_s_setprio(0);
    }
  }
#undef STAGE
  // ---- epilogue: lane l holds O[q = q0w + l31][dk = (r&3)+8*(r>>2)+4*hi (+32)] ----
  const int b = bh >> 4, h = bh & 15;
  const float inv = 1.0f / l_run;
  const int q = q0w + l31;
  ushort* orow = O + ((size_t)b * NL + q) * ND + h * NDK;
#pragma unroll
  for (int gi = 0; gi < 4; gi++) {
    ushort4 o0, o1;
    o0.x = f2bf(accO0[4 * gi + 0] * inv); o0.y = f2bf(accO0[4 * gi + 1] * inv);
    o0.z = f2bf(accO0[4 * gi + 2] * inv); o0.w = f2bf(accO0[4 * gi + 3] * inv);
    o1.x = f2bf(accO1[4 * gi + 0] * inv); o1.y = f2bf(accO1[4 * gi + 1] * inv);
    o1.z = f2bf(accO1[4 * gi + 2] * inv); o1.w = f2bf(accO1[4 * gi + 3] * inv);
    *(ushort4*)&orow[8 * gi + 4 * hi] = o0;
    *(ushort4*)&orow[32 + 8 * gi + 4 * hi] = o1;
  }
}

extern "C" void kernel_launch(void* const* d_in, const int* in_sizes, int n_in,
                              void* d_out, int out_size, void* d_ws, size_t ws_size,
                              hipStream_t stream) {
  const float* x = (const float*)d_in[0];
  const float* wq = (const float*)d_in[1];
  const float* wk = (const float*)d_in[2];
  const float* wv = (const float*)d_in[3];
  const float* wo = (const float*)d_in[4];
  char* ws = (char*)d_ws;
  ushort* xb  = (ushort*)(ws);               // 16,777,216 B
  ushort* wqb = (ushort*)(ws + 16777216);
  ushort* wkb = (ushort*)(ws + 18874368);
  ushort* wvb = (ushort*)(ws + 20971520);
  ushort* wob = (ushort*)(ws + 23068672);
  ushort* Qb  = (ushort*)(ws + 25165824);    // [B,H,L,DK] bf16, pre-scaled
  ushort* Kb  = (ushort*)(ws + 41943040);    // [B,H,L,DK]
  ushort* Vb  = (ushort*)(ws + 58720256);    // [B,H,DK,L] (transposed)
  ushort* Ob  = (ushort*)(ws + 75497472);    // [B,L,D] bf16

  convert_all<<<12288, 256, 0, stream>>>(x, wq, wk, wv, wo, xb);
  gemm_bt<0><<<dim3(64, 24), 256, 0, stream>>>(xb, wqb, wkb, wvb, Qb, Kb, Vb, nullptr);
  attn_fwd<<<dim3(1024), 256, 0, stream>>>(Qb, Kb, Vb, Ob);
  gemm_bt<1><<<dim3(64, 8), 256, 0, stream>>>(Ob, wob, nullptr, nullptr,
                                              nullptr, nullptr, nullptr, (float*)d_out);
}